// Round 1
// baseline (2756.435 us; speedup 1.0000x reference)
//
#include <hip/hip_runtime.h>
#include <math.h>

static constexpr int S = 2048;
static constexpr int D = 64;
static constexpr float MASK_FILL_NEG = -1e-12f;

// ---------------------------------------------------------------------------
// K1: scores[bh][s][t] = (Q[bh,s,:] . K[bh,t,:]) / 8, masked (mask==0 -> -1e-12)
// 64x64 output tile per block, K-dim = 64 (one LDS pass).
// Tiles stored transposed in LDS so the inner loop is 2x ds_read_b128 + 16 FMA.
// ---------------------------------------------------------------------------
__global__ __launch_bounds__(256) void scores_kernel(
    const float* __restrict__ q, const float* __restrict__ k,
    const int* __restrict__ masks, float* __restrict__ scores)
{
    __shared__ float Qt[64][68];  // [kdim][row], pad 68 keeps 16B align + banks spread
    __shared__ float Kt[64][68];  // [kdim][col]

    const int bh = blockIdx.z;        // 0..31  (b*16 + h)
    const int b  = bh >> 4;           // H = 16
    const int s0 = blockIdx.y * 64;
    const int t0 = blockIdx.x * 64;
    const int tid = threadIdx.x;

    const float4* qbase = (const float4*)(q + ((size_t)bh * S + s0) * D);
    const float4* kbase = (const float4*)(k + ((size_t)bh * S + t0) * D);

#pragma unroll
    for (int i = 0; i < 4; ++i) {
        const int f  = tid + 256 * i;   // float4 index 0..1023
        const int r  = f >> 4;          // row 0..63
        const int c4 = f & 15;          // float4 within row
        const int k0 = c4 * 4;
        float4 a = qbase[r * 16 + c4];
        Qt[k0 + 0][r] = a.x; Qt[k0 + 1][r] = a.y;
        Qt[k0 + 2][r] = a.z; Qt[k0 + 3][r] = a.w;
        float4 c = kbase[r * 16 + c4];
        Kt[k0 + 0][r] = c.x; Kt[k0 + 1][r] = c.y;
        Kt[k0 + 2][r] = c.z; Kt[k0 + 3][r] = c.w;
    }
    __syncthreads();

    const int r0 = (tid >> 4) * 4;
    const int c0 = (tid & 15) * 4;
    float acc[4][4] = {};

#pragma unroll
    for (int kk = 0; kk < 64; ++kk) {
        const float4 a  = *(const float4*)&Qt[kk][r0];
        const float4 bb = *(const float4*)&Kt[kk][c0];
        const float av[4] = {a.x, a.y, a.z, a.w};
        const float bv[4] = {bb.x, bb.y, bb.z, bb.w};
#pragma unroll
        for (int i = 0; i < 4; ++i)
#pragma unroll
            for (int j = 0; j < 4; ++j)
                acc[i][j] = fmaf(av[i], bv[j], acc[i][j]);
    }

#pragma unroll
    for (int i = 0; i < 4; ++i) {
        const int srow = s0 + r0 + i;
        const int4 mr = *(const int4*)(masks + ((size_t)b * S + srow) * S + t0 + c0);
        float4 o;
        o.x = (mr.x == 0) ? MASK_FILL_NEG : acc[i][0] * 0.125f;
        o.y = (mr.y == 0) ? MASK_FILL_NEG : acc[i][1] * 0.125f;
        o.z = (mr.z == 0) ? MASK_FILL_NEG : acc[i][2] * 0.125f;
        o.w = (mr.w == 0) ? MASK_FILL_NEG : acc[i][3] * 0.125f;
        *(float4*)(scores + ((size_t)bh * S + srow) * S + t0 + c0) = o;
    }
}

// ---------------------------------------------------------------------------
// K2: per (bh, 64-row tile):
//   out[rows,:] = scores[rows,:] @ V        (the faithful bug: raw scores)
//   attention[rows,:] = softmax(scores[rows,:])  (in-place over scores region)
// Online row max/sumexp tracked while tiles stream through LDS.
// ---------------------------------------------------------------------------
__global__ __launch_bounds__(256) void out_softmax_kernel(
    const float* __restrict__ v, float* __restrict__ scores,
    float* __restrict__ out)
{
    __shared__ float St[64][68];   // [t][row] transposed scores tile
    __shared__ float Vs[64][68];   // [t][d]
    __shared__ float pmax[4][64];
    __shared__ float psum[4][64];
    __shared__ float mrow[64];
    __shared__ float linv[64];

    const int bh = blockIdx.y;
    const int s0 = blockIdx.x * 64;
    const int tid = threadIdx.x;
    const int r0 = (tid >> 4) * 4;
    const int c0 = (tid & 15) * 4;
    const int qq = tid >> 6;   // quarter 0..3
    const int rr = tid & 63;   // row within tile

    float acc[4][4] = {};
    float m = -INFINITY, l = 0.0f;

    const float* vbase = v + (size_t)bh * S * D;
    float* srow_base = scores + (size_t)bh * S * S + (size_t)s0 * S;

    for (int kt = 0; kt < 32; ++kt) {
        const int t0k = kt * 64;
        // ---- stage ----
#pragma unroll
        for (int i = 0; i < 4; ++i) {
            const int f  = tid + 256 * i;
            const int r  = f >> 4;
            const int c4 = f & 15;
            const int t4 = c4 * 4;
            float4 sv = *(const float4*)&srow_base[(size_t)r * S + t0k + t4];
            St[t4 + 0][r] = sv.x; St[t4 + 1][r] = sv.y;
            St[t4 + 2][r] = sv.z; St[t4 + 3][r] = sv.w;
            float4 vv = *(const float4*)&vbase[(size_t)(t0k + r) * D + t4];
            *(float4*)&Vs[r][t4] = vv;
        }
        __syncthreads();

        // ---- partial softmax stats (4 threads per row, 16 elems each) ----
        {
            float pm = -INFINITY;
#pragma unroll
            for (int t = 0; t < 16; ++t) pm = fmaxf(pm, St[qq * 16 + t][rr]);
            float ps = 0.0f;
#pragma unroll
            for (int t = 0; t < 16; ++t) ps += __expf(St[qq * 16 + t][rr] - pm);
            pmax[qq][rr] = pm;
            psum[qq][rr] = ps;
        }

        // ---- GEMM: acc += S_tile @ V_tile ----
#pragma unroll
        for (int t = 0; t < 64; ++t) {
            const float4 a  = *(const float4*)&St[t][r0];
            const float4 bb = *(const float4*)&Vs[t][c0];
            const float av[4] = {a.x, a.y, a.z, a.w};
            const float bv[4] = {bb.x, bb.y, bb.z, bb.w};
#pragma unroll
            for (int i = 0; i < 4; ++i)
#pragma unroll
                for (int j = 0; j < 4; ++j)
                    acc[i][j] = fmaf(av[i], bv[j], acc[i][j]);
        }
        __syncthreads();

        // ---- combine partials (one thread per row) ----
        if (tid < 64) {
            float m2 = m;
#pragma unroll
            for (int q2 = 0; q2 < 4; ++q2) m2 = fmaxf(m2, pmax[q2][tid]);
            l = l * __expf(m - m2);
#pragma unroll
            for (int q2 = 0; q2 < 4; ++q2)
                l += psum[q2][tid] * __expf(pmax[q2][tid] - m2);
            m = m2;
        }
        // (safe: combiners re-sync at next iteration's barrier before pmax reuse)
    }

    // ---- write out ----
    float* obase = out + ((size_t)bh * S + s0) * D;
#pragma unroll
    for (int i = 0; i < 4; ++i) {
        float4 o = make_float4(acc[i][0], acc[i][1], acc[i][2], acc[i][3]);
        *(float4*)&obase[(size_t)(r0 + i) * D + c0] = o;
    }

    if (tid < 64) { mrow[tid] = m; linv[tid] = 1.0f / l; }
    __syncthreads();

    // ---- attention write: in-place exp(s - m) / l over this block's 64 rows ----
    for (int r = 0; r < 64; ++r) {
        const float mr = mrow[r];
        const float li = linv[r];
        float4* row = (float4*)(srow_base + (size_t)r * S);
#pragma unroll
        for (int t4 = tid; t4 < S / 4; t4 += 256) {
            float4 x = row[t4];
            x.x = __expf(x.x - mr) * li;
            x.y = __expf(x.y - mr) * li;
            x.z = __expf(x.z - mr) * li;
            x.w = __expf(x.w - mr) * li;
            row[t4] = x;
        }
    }
}

extern "C" void kernel_launch(void* const* d_in, const int* in_sizes, int n_in,
                              void* d_out, int out_size, void* d_ws, size_t ws_size,
                              hipStream_t stream) {
    const float* q     = (const float*)d_in[0];
    const float* k     = (const float*)d_in[1];
    const float* v     = (const float*)d_in[2];
    const int*   masks = (const int*)d_in[3];

    float* out  = (float*)d_out;                       // [2,16,2048,64] = 4194304
    float* attn = out + (size_t)2 * 16 * S * D;        // [2,16,2048,2048]

    dim3 g1(S / 64, S / 64, 32);
    scores_kernel<<<g1, 256, 0, stream>>>(q, k, masks, attn);

    dim3 g2(S / 64, 32);
    out_softmax_kernel<<<g2, 256, 0, stream>>>(v, attn, out);
}

// Round 2
// 816.814 us; speedup vs baseline: 3.3746x; 3.3746x over previous
//
#include <hip/hip_runtime.h>
#include <math.h>

static constexpr int S  = 2048;
static constexpr int D  = 64;
static constexpr int BH = 32;   // B*H = 2*16

typedef __bf16 bf16;
typedef __bf16 bf16x8 __attribute__((ext_vector_type(8)));
typedef float  f32x4  __attribute__((ext_vector_type(4)));

__device__ __forceinline__ int swz(int row, int chunk) { return chunk ^ (row & 7); }

__device__ __forceinline__ f32x4 mfma16(bf16x8 a, bf16x8 b, f32x4 c) {
    return __builtin_amdgcn_mfma_f32_16x16x32_bf16(a, b, c, 0, 0, 0);
}

// Stage a 64x64 fp32 tile (row-major, row stride 64) into LDS as bf16,
// row-major with XOR-swizzled 16B chunks: element (r,k) -> r*64 + (k>>3 ^ (r&7))*8 + (k&7)
__device__ __forceinline__ void stage_rowmajor(const float* __restrict__ src,
                                               bf16* dst, int tid) {
#pragma unroll
    for (int u = 0; u < 2; ++u) {
        const int id  = tid + u * 256;      // chunk id 0..511
        const int row = id >> 3;
        const int c   = id & 7;
        const float4* p = (const float4*)(src + row * 64 + c * 8);
        float4 a = p[0], b = p[1];
        bf16x8 v;
        v[0] = (bf16)a.x; v[1] = (bf16)a.y; v[2] = (bf16)a.z; v[3] = (bf16)a.w;
        v[4] = (bf16)b.x; v[5] = (bf16)b.y; v[6] = (bf16)b.z; v[7] = (bf16)b.w;
        *(bf16x8*)(dst + row * 64 + swz(row, c) * 8) = v;
    }
}

// Stage V tile transposed: Vt[d][t] (row stride 64, same swizzle on t-chunks)
__device__ __forceinline__ void stage_vT(const float* __restrict__ vsrc,
                                         bf16* dst, int tid) {
#pragma unroll
    for (int u = 0; u < 2; ++u) {
        const int id = tid + u * 256;       // unit: t = id&63, d0 = (id>>6)*8
        const int t  = id & 63;
        const int d0 = (id >> 6) * 8;
        const float4* p = (const float4*)(vsrc + t * 64 + d0);
        float4 a = p[0], b = p[1];
        const float dv[8] = {a.x, a.y, a.z, a.w, b.x, b.y, b.z, b.w};
#pragma unroll
        for (int j = 0; j < 8; ++j) {
            const int d = d0 + j;
            dst[d * 64 + swz(d, t >> 3) * 8 + (t & 7)] = (bf16)dv[j];
        }
    }
}

// ---------------------------------------------------------------------------
// P0: bit-pack masks [2][S][S] int32 -> [2][S][S/32] u32 (1 MiB, L2-resident)
// ---------------------------------------------------------------------------
__global__ __launch_bounds__(256) void p0_bitpack(const int* __restrict__ masks,
                                                  unsigned* __restrict__ mbits) {
    const int idx = blockIdx.x * 256 + threadIdx.x;   // (b*S+s)*64 + w
    const int4* p = (const int4*)(masks + (size_t)idx * 32);
    unsigned word = 0;
#pragma unroll
    for (int i = 0; i < 8; ++i) {
        int4 m = p[i];
        word |= (m.x != 0 ? 1u : 0u) << (i * 4 + 0);
        word |= (m.y != 0 ? 1u : 0u) << (i * 4 + 1);
        word |= (m.z != 0 ? 1u : 0u) << (i * 4 + 2);
        word |= (m.w != 0 ? 1u : 0u) << (i * 4 + 3);
    }
    mbits[idx] = word;
}

// ---------------------------------------------------------------------------
// P1: out = (masked scaled scores) @ V   [MFMA, faithful bug: raw scores]
//     linv[row] = 1 / sum_t exp(score)   (no max-shift needed: |s| ~ O(6))
// One block per (bh, 64-row tile). 4 waves, each owns a 16-row strip.
// ---------------------------------------------------------------------------
__global__ __launch_bounds__(256) void p1_out_stats(
    const float* __restrict__ q, const float* __restrict__ k,
    const float* __restrict__ v, const unsigned* __restrict__ mbits,
    float* __restrict__ out, float* __restrict__ linv) {
    __shared__ __align__(16) bf16 Qs[64 * 64];
    __shared__ __align__(16) bf16 Ks[64 * 64];
    __shared__ __align__(16) bf16 Vt[64 * 64];
    __shared__ __align__(16) bf16 Sb[4][16 * 64];   // per-wave private strip

    const int bh   = blockIdx.x;
    const int s0   = blockIdx.y * 64;
    const int b    = bh >> 4;
    const int tid  = threadIdx.x;
    const int w    = tid >> 6;
    const int lane = tid & 63;
    const int col  = lane & 15;
    const int quad = lane >> 4;

    stage_rowmajor(q + ((size_t)bh * S + s0) * D, Qs, tid);
    __syncthreads();

    const int ar = w * 16 + col;               // A-operand row (m = lane&15)
    bf16x8 aQ0 = *(bf16x8*)(Qs + ar * 64 + swz(ar, quad) * 8);
    bf16x8 aQ1 = *(bf16x8*)(Qs + ar * 64 + swz(ar, 4 + quad) * 8);

    f32x4 oacc[4] = {};
    float l[4] = {0.f, 0.f, 0.f, 0.f};
    const float* kb = k + (size_t)bh * S * D;
    const float* vb = v + (size_t)bh * S * D;

    const unsigned* mrow[4];
#pragma unroll
    for (int r = 0; r < 4; ++r)
        mrow[r] = mbits + (size_t)(b * S + s0 + w * 16 + quad * 4 + r) * 64;

    for (int kt = 0; kt < 32; ++kt) {
        __syncthreads();
        stage_rowmajor(kb + (size_t)kt * 64 * D, Ks, tid);
        stage_vT(vb + (size_t)kt * 64 * D, Vt, tid);
        __syncthreads();

        unsigned mw[4][2];
#pragma unroll
        for (int r = 0; r < 4; ++r) {
            mw[r][0] = mrow[r][kt * 2 + 0];
            mw[r][1] = mrow[r][kt * 2 + 1];
        }

        // ---- QK^T, mask+scale, exp-sum, stash S (bf16) in A-layout strip ----
#pragma unroll
        for (int ct = 0; ct < 4; ++ct) {
            const int br = ct * 16 + col;      // K row (t)
            bf16x8 b0 = *(bf16x8*)(Ks + br * 64 + swz(br, quad) * 8);
            bf16x8 b1 = *(bf16x8*)(Ks + br * 64 + swz(br, 4 + quad) * 8);
            f32x4 s = {};
            s = mfma16(aQ0, b0, s);
            s = mfma16(aQ1, b1, s);
            const int t   = ct * 16 + col;
            const int pos = t & 31;
#pragma unroll
            for (int r = 0; r < 4; ++r) {
                const float sv = ((mw[r][ct >> 1] >> pos) & 1u)
                                     ? s[r] * 0.125f : -1e-12f;
                l[r] += __expf(sv);
                const int sr = quad * 4 + r;   // C-layout row within strip
                Sb[w][sr * 64 + swz(sr, t >> 3) * 8 + (t & 7)] = (bf16)sv;
            }
        }

        // ---- out += S @ V (wave-private strip, no barrier needed) ----
        bf16x8 aS0 = *(bf16x8*)(&Sb[w][col * 64 + swz(col, quad) * 8]);
        bf16x8 aS1 = *(bf16x8*)(&Sb[w][col * 64 + swz(col, 4 + quad) * 8]);
#pragma unroll
        for (int dt = 0; dt < 4; ++dt) {
            const int vr = dt * 16 + col;      // Vt row (d)
            bf16x8 b0 = *(bf16x8*)(Vt + vr * 64 + swz(vr, quad) * 8);
            bf16x8 b1 = *(bf16x8*)(Vt + vr * 64 + swz(vr, 4 + quad) * 8);
            oacc[dt] = mfma16(aS0, b0, oacc[dt]);
            oacc[dt] = mfma16(aS1, b1, oacc[dt]);
        }
    }

    // ---- epilogue: out rows (s0 + w*16 + quad*4 + r), cols (dt*16 + col) ----
    float* ob = out + ((size_t)bh * S + s0 + w * 16 + quad * 4) * D;
#pragma unroll
    for (int dt = 0; dt < 4; ++dt)
#pragma unroll
        for (int r = 0; r < 4; ++r)
            ob[(size_t)r * D + dt * 16 + col] = oacc[dt][r];

#pragma unroll
    for (int r = 0; r < 4; ++r) {
        float x = l[r];
        x += __shfl_xor(x, 1, 16);
        x += __shfl_xor(x, 2, 16);
        x += __shfl_xor(x, 4, 16);
        x += __shfl_xor(x, 8, 16);
        if (col == 0)
            linv[(size_t)bh * S + s0 + w * 16 + quad * 4 + r] = 1.0f / x;
    }
}

// ---------------------------------------------------------------------------
// P2: recompute scores, write attn = exp(score) * linv[row]  (512 MiB stream)
// ---------------------------------------------------------------------------
__global__ __launch_bounds__(256) void p2_attn(
    const float* __restrict__ q, const float* __restrict__ k,
    const unsigned* __restrict__ mbits, const float* __restrict__ linv,
    float* __restrict__ attn) {
    __shared__ __align__(16) bf16 Qs[64 * 64];
    __shared__ __align__(16) bf16 Ks[64 * 64];

    const int bh   = blockIdx.x;
    const int s0   = blockIdx.y * 64;
    const int b    = bh >> 4;
    const int tid  = threadIdx.x;
    const int w    = tid >> 6;
    const int lane = tid & 63;
    const int col  = lane & 15;
    const int quad = lane >> 4;

    stage_rowmajor(q + ((size_t)bh * S + s0) * D, Qs, tid);
    __syncthreads();

    const int ar = w * 16 + col;
    bf16x8 aQ0 = *(bf16x8*)(Qs + ar * 64 + swz(ar, quad) * 8);
    bf16x8 aQ1 = *(bf16x8*)(Qs + ar * 64 + swz(ar, 4 + quad) * 8);

    float li[4];
    const unsigned* mrow[4];
#pragma unroll
    for (int r = 0; r < 4; ++r) {
        const int srow = s0 + w * 16 + quad * 4 + r;
        li[r]   = linv[(size_t)bh * S + srow];
        mrow[r] = mbits + (size_t)(b * S + srow) * 64;
    }

    const float* kb = k + (size_t)bh * S * D;
    float* ab = attn + ((size_t)bh * S + s0 + w * 16 + quad * 4) * (size_t)S;

    for (int kt = 0; kt < 32; ++kt) {
        __syncthreads();
        stage_rowmajor(kb + (size_t)kt * 64 * D, Ks, tid);
        __syncthreads();

        unsigned mw[4][2];
#pragma unroll
        for (int r = 0; r < 4; ++r) {
            mw[r][0] = mrow[r][kt * 2 + 0];
            mw[r][1] = mrow[r][kt * 2 + 1];
        }

#pragma unroll
        for (int ct = 0; ct < 4; ++ct) {
            const int br = ct * 16 + col;
            bf16x8 b0 = *(bf16x8*)(Ks + br * 64 + swz(br, quad) * 8);
            bf16x8 b1 = *(bf16x8*)(Ks + br * 64 + swz(br, 4 + quad) * 8);
            f32x4 s = {};
            s = mfma16(aQ0, b0, s);
            s = mfma16(aQ1, b1, s);
            const int t   = ct * 16 + col;
            const int pos = t & 31;
#pragma unroll
            for (int r = 0; r < 4; ++r) {
                const float sv = ((mw[r][ct >> 1] >> pos) & 1u)
                                     ? s[r] * 0.125f : -1e-12f;
                ab[(size_t)r * S + kt * 64 + t] = __expf(sv) * li[r];
            }
        }
    }
}

extern "C" void kernel_launch(void* const* d_in, const int* in_sizes, int n_in,
                              void* d_out, int out_size, void* d_ws, size_t ws_size,
                              hipStream_t stream) {
    const float* q     = (const float*)d_in[0];
    const float* k     = (const float*)d_in[1];
    const float* v     = (const float*)d_in[2];
    const int*   masks = (const int*)d_in[3];

    float* out  = (float*)d_out;                 // [2,16,S,D]
    float* attn = out + (size_t)BH * S * D;      // [2,16,S,S]

    unsigned* mbits = (unsigned*)d_ws;                               // 1 MiB
    float*    linvp = (float*)((char*)d_ws + (size_t)2 * S * 64 * 4); // 256 KiB

    p0_bitpack<<<(2 * S * 64) / 256, 256, 0, stream>>>(masks, mbits);

    dim3 g(BH, S / 64);   // x = bh (XCD round-robin keeps per-XCD K/Q hot set small)
    p1_out_stats<<<g, 256, 0, stream>>>(q, k, v, mbits, out, linvp);
    p2_attn<<<g, 256, 0, stream>>>(q, k, mbits, linvp, attn);
}